// Round 1
// baseline (671.863 us; speedup 1.0000x reference)
//
#include <hip/hip_runtime.h>
#include <hip/hip_bf16.h>

#define NODELEN 17949
#define NN 512
#define NE 4096
#define H2 768
#define EMB 128
#define IN_DIM (2 * NODELEN)      // 35898
#define KP1 35904                 // IN_DIM padded to 64 (561 * 64)
#define KITERS1 561
#define SPLITS 16
#define KCHUNK1 36                // ceil(561/16)

#define BM 128
#define BN 128
#define BK 64
#define LDT (BK + 8)              // LDS row stride in bf16 (pad 16B)

typedef __bf16 bf16x8 __attribute__((ext_vector_type(8)));
typedef float f32x4 __attribute__((ext_vector_type(4)));

// ---------------- graph prep ----------------

__global__ void k_zero_int(int* p, int n) {
    int i = blockIdx.x * 256 + threadIdx.x;
    if (i < n) p[i] = 0;
}

__global__ void k_deg(const int* __restrict__ dst, int* __restrict__ cnt) {
    int e = blockIdx.x * 256 + threadIdx.x;
    if (e < NE) atomicAdd(&cnt[dst[e]], 1);
}

__global__ void k_scan(const int* __restrict__ cnt, int* __restrict__ offs,
                       float* __restrict__ invdeg) {
    __shared__ int s[NN];
    int t = threadIdx.x;
    int c = cnt[t];
    s[t] = c;
    int cd = c > 1 ? c : 1;
    invdeg[t] = 1.0f / (float)cd;
    __syncthreads();
    for (int d = 1; d < NN; d <<= 1) {
        int add = (t >= d) ? s[t - d] : 0;
        __syncthreads();
        s[t] += add;
        __syncthreads();
    }
    offs[t + 1] = s[t];
    if (t == 0) offs[0] = 0;
}

__global__ void k_fill(const int* __restrict__ src, const int* __restrict__ dst,
                       const int* __restrict__ offs, int* __restrict__ cursor,
                       int* __restrict__ csr) {
    int e = blockIdx.x * 256 + threadIdx.x;
    if (e < NE) {
        int d = dst[e];
        int pos = offs[d] + atomicAdd(&cursor[d], 1);
        csr[pos] = src[e];
    }
}

// out[n][f] = mean over in-edges of in[src][f]; col 0 zeroed
__global__ void k_agg(const float* __restrict__ in, float* __restrict__ out,
                      const int* __restrict__ csr, const int* __restrict__ offs,
                      const float* __restrict__ invdeg) {
    int f = blockIdx.x * 256 + threadIdx.x;
    int n = blockIdx.y;
    if (f >= NODELEN) return;
    int e0 = offs[n], e1 = offs[n + 1];
    float s = 0.f;
    for (int e = e0; e < e1; ++e) {
        s += in[(size_t)csr[e] * NODELEN + f];
    }
    float v = (f == 0) ? 0.f : s * invdeg[n];
    out[(size_t)n * NODELEN + f] = v;
}

// embb[n][c] bf16: c<NODELEN -> x (c==0 zero); c<IN_DIM -> h2; else pad 0
__global__ void k_emb(const float* __restrict__ x, const float* __restrict__ h2,
                      __bf16* __restrict__ embb) {
    int c = blockIdx.x * 256 + threadIdx.x;
    int n = blockIdx.y;
    if (c >= KP1) return;
    float v;
    if (c < NODELEN) v = (c == 0) ? 0.f : x[(size_t)n * NODELEN + c];
    else if (c < IN_DIM) v = h2[(size_t)n * NODELEN + (c - NODELEN)];
    else v = 0.f;
    embb[(size_t)n * KP1 + c] = (__bf16)v;
}

// ---------------- MFMA GEMM: C[m][n] = sum_k A_bf16[m][k] * B_f32[n][k] ----------------
// A row-major bf16 (lda), B row-major fp32 (ldb), both K-contiguous.
// PARTIAL: write per-split partials[z][512][768]; else C[m*ldc+n] (+bias) with n<Nvalid.

template <bool PARTIAL, bool BIAS>
__global__ __launch_bounds__(256) void gemm_bf16(
        const __bf16* __restrict__ A, int lda,
        const float* __restrict__ B, int ldb,
        int Nvalid, int Kvalid, int kIters, int kChunk,
        float* __restrict__ C, int ldc,
        const float* __restrict__ bias,
        float* __restrict__ partials) {
    __shared__ __align__(16) __bf16 As[BM][LDT];
    __shared__ __align__(16) __bf16 Bs[BN][LDT];

    const int tid = threadIdx.x;
    const int m0 = blockIdx.x * BM;
    const int n0 = blockIdx.y * BN;
    const int z = blockIdx.z;

    int it0 = z * kChunk;
    int it1 = it0 + kChunk;
    if (it1 > kIters) it1 = kIters;

    const int wave = tid >> 6;
    const int lane = tid & 63;
    const int wm = (wave & 1) * 64;
    const int wn = (wave >> 1) * 64;
    const int fl = lane & 15;
    const int fq = lane >> 4;

    const int srow = tid >> 1;       // 0..127 (shared by A and B staging)
    const int spart = tid & 1;       // 0/1 -> k offset 0/32

    f32x4 acc[4][4] = {};

    const int bn = n0 + srow;
    const bool nok = bn < Nvalid;

    for (int it = it0; it < it1; ++it) {
        int k0 = it * BK;

        // stage A: 32 bf16 per thread (64B) -> LDS
        {
            const uint4* Ag = (const uint4*)(A + (size_t)(m0 + srow) * lda + k0 + spart * 32);
            uint4 av[4];
#pragma unroll
            for (int i = 0; i < 4; ++i) av[i] = Ag[i];
#pragma unroll
            for (int i = 0; i < 4; ++i)
                *(uint4*)&As[srow][spart * 32 + i * 8] = av[i];
        }
        // stage B: 32 fp32 per thread, convert to bf16 -> LDS
        {
            __align__(16) __bf16 bl[32];
            if (nok && (k0 + BK) <= Kvalid) {
                const float2* Bg = (const float2*)(B + (size_t)bn * ldb + k0 + spart * 32);
                float2 f[16];
#pragma unroll
                for (int j = 0; j < 16; ++j) f[j] = Bg[j];
#pragma unroll
                for (int j = 0; j < 16; ++j) {
                    bl[2 * j] = (__bf16)f[j].x;
                    bl[2 * j + 1] = (__bf16)f[j].y;
                }
            } else {
#pragma unroll
                for (int j = 0; j < 32; ++j) {
                    int kk = k0 + spart * 32 + j;
                    float v = (nok && kk < Kvalid) ? B[(size_t)bn * ldb + kk] : 0.f;
                    bl[j] = (__bf16)v;
                }
            }
#pragma unroll
            for (int q = 0; q < 4; ++q)
                *(uint4*)&Bs[srow][spart * 32 + q * 8] = *(uint4*)&bl[q * 8];
        }
        __syncthreads();

#pragma unroll
        for (int ks = 0; ks < 2; ++ks) {
            int kk = ks * 32 + fq * 8;
            bf16x8 af[4], bf[4];
#pragma unroll
            for (int i = 0; i < 4; ++i)
                af[i] = *(const bf16x8*)&As[wm + i * 16 + fl][kk];
#pragma unroll
            for (int j = 0; j < 4; ++j)
                bf[j] = *(const bf16x8*)&Bs[wn + j * 16 + fl][kk];
#pragma unroll
            for (int i = 0; i < 4; ++i)
#pragma unroll
                for (int j = 0; j < 4; ++j)
                    acc[i][j] = __builtin_amdgcn_mfma_f32_16x16x32_bf16(
                        af[i], bf[j], acc[i][j], 0, 0, 0);
        }
        __syncthreads();
    }

    // epilogue
#pragma unroll
    for (int i = 0; i < 4; ++i) {
#pragma unroll
        for (int j = 0; j < 4; ++j) {
#pragma unroll
            for (int r = 0; r < 4; ++r) {
                int m = m0 + wm + i * 16 + fq * 4 + r;
                int n = n0 + wn + j * 16 + fl;
                float v = acc[i][j][r];
                if (PARTIAL) {
                    partials[((size_t)z * (BM * 4) + m) * H2 + n] = v;
                } else {
                    if (n < Nvalid) {
                        if (BIAS) v += bias[n];
                        C[(size_t)m * ldc + n] = v;
                    }
                }
            }
        }
    }
}

// h = relu(sum_z partials + b_e2)
__global__ void k_reduce(const float* __restrict__ partials,
                         const float* __restrict__ bias, float* __restrict__ h) {
    int idx = blockIdx.x * 256 + threadIdx.x;
    if (idx >= NN * H2) return;
    float s = 0.f;
#pragma unroll
    for (int z = 0; z < SPLITS; ++z) s += partials[(size_t)z * NN * H2 + idx];
    s += bias[idx % H2];
    h[idx] = s > 0.f ? s : 0.f;
}

// encoded[m][e] = h[m] . W_e3[e] + b_e3[e]   (512 blocks x 128 threads)
__global__ void k_enc(const float* __restrict__ h, const float* __restrict__ W,
                      const float* __restrict__ b, float* __restrict__ out) {
    int m = blockIdx.x, e = threadIdx.x;
    const float4* hr = (const float4*)(h + (size_t)m * H2);
    const float4* wr = (const float4*)(W + (size_t)e * H2);
    float s = 0.f;
#pragma unroll 4
    for (int i = 0; i < H2 / 4; ++i) {
        float4 a = hr[i];
        float4 w = wr[i];
        s += a.x * w.x + a.y * w.y + a.z * w.z + a.w * w.w;
    }
    out[(size_t)m * EMB + e] = s + b[e];
}

// hd_b[m][j] = bf16(relu(enc[m] . W_d1[j] + b_d1[j]))  (512 blocks x 256 threads)
__global__ void k_dec1(const float* __restrict__ enc, const float* __restrict__ W,
                       const float* __restrict__ b, __bf16* __restrict__ hd) {
    int m = blockIdx.x;
    __shared__ float er[EMB];
    if (threadIdx.x < EMB) er[threadIdx.x] = enc[(size_t)m * EMB + threadIdx.x];
    __syncthreads();
    for (int j = threadIdx.x; j < H2; j += 256) {
        const float4* wr = (const float4*)(W + (size_t)j * EMB);
        float s = 0.f;
#pragma unroll
        for (int i = 0; i < EMB / 4; ++i) {
            float4 w = wr[i];
            s += w.x * er[4 * i] + w.y * er[4 * i + 1] + w.z * er[4 * i + 2] +
                 w.w * er[4 * i + 3];
        }
        float v = s + b[j];
        hd[(size_t)m * H2 + j] = (__bf16)(v > 0.f ? v : 0.f);
    }
}

// ---------------- launch ----------------

extern "C" void kernel_launch(void* const* d_in, const int* in_sizes, int n_in,
                              void* d_out, int out_size, void* d_ws, size_t ws_size,
                              hipStream_t stream) {
    const float* x = (const float*)d_in[0];
    const int* esrc = (const int*)d_in[1];
    const int* edst = (const int*)d_in[2];
    const float* W_e2 = (const float*)d_in[3];
    const float* b_e2 = (const float*)d_in[4];
    const float* W_e3 = (const float*)d_in[5];
    const float* b_e3 = (const float*)d_in[6];
    const float* W_d1 = (const float*)d_in[7];
    const float* b_d1 = (const float*)d_in[8];
    const float* W_d3 = (const float*)d_in[9];
    const float* b_d3 = (const float*)d_in[10];
    float* out = (float*)d_out;

    char* w = (char*)d_ws;
    auto alloc = [&](size_t bytes) {
        char* p = w;
        w += (bytes + 255) & ~(size_t)255;
        return p;
    };
    float* partials = (float*)alloc((size_t)SPLITS * NN * H2 * 4);
    float* h1 = (float*)alloc((size_t)NN * NODELEN * 4);
    float* h2 = (float*)alloc((size_t)NN * NODELEN * 4);
    __bf16* embb = (__bf16*)alloc((size_t)NN * KP1 * 2);
    float* h = (float*)alloc((size_t)NN * H2 * 4);
    __bf16* hd_b = (__bf16*)alloc((size_t)NN * H2 * 2);
    int* cnt = (int*)alloc(NN * 4);
    int* cursor = (int*)alloc(NN * 4);
    int* offs = (int*)alloc((NN + 1) * 4);
    int* csr = (int*)alloc(NE * 4);
    float* invdeg = (float*)alloc(NN * 4);

    // graph prep
    k_zero_int<<<4, 256, 0, stream>>>(cnt, NN);
    k_zero_int<<<4, 256, 0, stream>>>(cursor, NN);
    k_deg<<<NE / 256, 256, 0, stream>>>(edst, cnt);
    k_scan<<<1, NN, 0, stream>>>(cnt, offs, invdeg);
    k_fill<<<NE / 256, 256, 0, stream>>>(esrc, edst, offs, cursor, csr);

    // 2-hop mean aggregation
    dim3 gagg((NODELEN + 255) / 256, NN);
    k_agg<<<gagg, 256, 0, stream>>>(x, h1, csr, offs, invdeg);
    k_agg<<<gagg, 256, 0, stream>>>(h1, h2, csr, offs, invdeg);

    // build bf16 emb (padded K)
    dim3 gemb((KP1 + 255) / 256, NN);
    k_emb<<<gemb, 256, 0, stream>>>(x, h2, embb);

    // GEMM1: emb @ W_e2^T (split-K partials)
    dim3 g1(NN / BM, H2 / BN, SPLITS);
    gemm_bf16<true, false><<<g1, 256, 0, stream>>>(
        embb, KP1, W_e2, IN_DIM, H2, IN_DIM, KITERS1, KCHUNK1,
        (float*)nullptr, 0, (const float*)nullptr, partials);

    // h = relu(sum + b_e2)
    k_reduce<<<(NN * H2) / 256, 256, 0, stream>>>(partials, b_e2, h);

    // encoded -> d_out[0 .. 512*128)
    k_enc<<<NN, EMB, 0, stream>>>(h, W_e3, b_e3, out);

    // h_d = relu(enc @ W_d1^T + b_d1), bf16
    k_dec1<<<NN, 256, 0, stream>>>(out, W_d1, b_d1, hd_b);

    // GEMM4: decoded = h_d @ W_d3^T + b_d3 -> d_out[512*128 ..)
    dim3 g4(NN / BM, (IN_DIM + BN - 1) / BN, 1);
    gemm_bf16<false, true><<<g4, 256, 0, stream>>>(
        hd_b, H2, W_d3, H2, IN_DIM, H2, H2 / BK, H2 / BK,
        out + (size_t)NN * EMB, IN_DIM, b_d3, (float*)nullptr);
}

// Round 2
// 591.705 us; speedup vs baseline: 1.1355x; 1.1355x over previous
//
#include <hip/hip_runtime.h>
#include <hip/hip_bf16.h>

#define NODELEN 17949
#define NN 512
#define NE 4096
#define H2 768
#define EMB 128
#define IN_DIM (2 * NODELEN)      // 35898
#define KP1 35904                 // IN_DIM padded to 64 (561 * 64)
#define KITERS1 561
#define SPLITS 24
#define KCHUNK1 24                // ceil(561/24)

#define BM 128
#define BN 128
#define BK 64
#define LDT (BK + 8)              // LDS row stride in bf16 (pad 16B)

typedef __bf16 bf16x8 __attribute__((ext_vector_type(8)));
typedef float f32x4 __attribute__((ext_vector_type(4)));

// ---------------- graph prep (dense adjacency) ----------------

__global__ void k_zero_int(int* p, int n) {
    int i = blockIdx.x * 256 + threadIdx.x;
    if (i < n) p[i] = 0;
}

__global__ void k_zero_f4(float4* p, int n4) {
    int i = blockIdx.x * 256 + threadIdx.x;
    if (i < n4) p[i] = make_float4(0.f, 0.f, 0.f, 0.f);
}

__global__ void k_deg(const int* __restrict__ dst, int* __restrict__ cnt) {
    int e = blockIdx.x * 256 + threadIdx.x;
    if (e < NE) atomicAdd(&cnt[dst[e]], 1);
}

__global__ void k_invdeg(const int* __restrict__ cnt, float* __restrict__ invdeg) {
    int i = blockIdx.x * 256 + threadIdx.x;
    if (i < NN) {
        int c = cnt[i];
        invdeg[i] = 1.0f / (float)(c > 1 ? c : 1);
    }
}

// A[dst][src] += 1/deg[dst]  (duplicates accumulate identical values -> order-safe)
__global__ void k_scatter(const int* __restrict__ src, const int* __restrict__ dst,
                          const float* __restrict__ invdeg, float* __restrict__ A) {
    int e = blockIdx.x * 256 + threadIdx.x;
    if (e < NE) {
        int d = dst[e];
        atomicAdd(&A[(size_t)d * NN + src[e]], invdeg[d]);
    }
}

// A2b = bf16(A @ A), exploiting row sparsity (uniform branch on broadcast value)
__global__ void k_a2(const float* __restrict__ A, __bf16* __restrict__ A2b) {
    int i = blockIdx.x;
    int t = threadIdx.x;   // 256
    __shared__ float row[NN];
    row[t] = A[(size_t)i * NN + t];
    row[t + 256] = A[(size_t)i * NN + 256 + t];
    __syncthreads();
    float a0 = 0.f, a1 = 0.f;
    for (int s = 0; s < NN; ++s) {
        float a = row[s];
        if (a != 0.f) {
            a0 += a * A[(size_t)s * NN + t];
            a1 += a * A[(size_t)s * NN + 256 + t];
        }
    }
    A2b[(size_t)i * NN + t] = (__bf16)a0;
    A2b[(size_t)i * NN + 256 + t] = (__bf16)a1;
}

// xT[f][s] = bf16(x[s][f]) : tiled 64x64 transpose
__global__ void k_xt(const float* __restrict__ x, __bf16* __restrict__ xT) {
    __shared__ float t[64][65];
    int f0 = blockIdx.x * 64, s0 = blockIdx.y * 64;
    int tx = threadIdx.x & 63, ty = threadIdx.x >> 6;   // ty 0..3
#pragma unroll
    for (int r = 0; r < 16; ++r) {
        int f = f0 + tx;
        t[ty * 16 + r][tx] = (f < NODELEN) ? x[(size_t)(s0 + ty * 16 + r) * NODELEN + f] : 0.f;
    }
    __syncthreads();
#pragma unroll
    for (int r = 0; r < 16; ++r) {
        int f = f0 + ty * 16 + r;
        if (f < NODELEN) xT[(size_t)f * NN + s0 + tx] = (__bf16)t[tx][ty * 16 + r];
    }
}

// embb x-half: col0 zero; plus zero pad cols [IN_DIM, KP1)
__global__ void k_embx(const float* __restrict__ x, __bf16* __restrict__ embb) {
    int c = blockIdx.x * 256 + threadIdx.x;
    int n = blockIdx.y;
    if (c < NODELEN) {
        float v = (c == 0) ? 0.f : x[(size_t)n * NODELEN + c];
        embb[(size_t)n * KP1 + c] = (__bf16)v;
    } else {
        int cc = c - NODELEN;
        if (cc < KP1 - IN_DIM) embb[(size_t)n * KP1 + IN_DIM + cc] = (__bf16)0.f;
    }
}

// W_e2b[r][c] = bf16(W_e2[r][c]) padded to KP1 cols with zeros
__global__ void k_cvt_we2(const float* __restrict__ W, __bf16* __restrict__ Wb) {
    const int C8 = KP1 / 8;   // 4488
    int idx = blockIdx.x * 256 + threadIdx.x;
    if (idx >= H2 * C8) return;
    int r = idx / C8, c8 = (idx % C8) * 8;
    __align__(16) __bf16 o[8];
    if (c8 + 8 <= IN_DIM) {
        const float2* p = (const float2*)(W + (size_t)r * IN_DIM + c8);
#pragma unroll
        for (int j = 0; j < 4; ++j) {
            float2 f = p[j];
            o[2 * j] = (__bf16)f.x;
            o[2 * j + 1] = (__bf16)f.y;
        }
    } else {
#pragma unroll
        for (int j = 0; j < 8; ++j) {
            int c = c8 + j;
            o[j] = (c < IN_DIM) ? (__bf16)W[(size_t)r * IN_DIM + c] : (__bf16)0.f;
        }
    }
    *(uint4*)&Wb[(size_t)r * KP1 + c8] = *(uint4*)o;
}

// ---------------- MFMA GEMM: C[m][n] = sum_k A_bf16[m][k] * B[n][k] ----------------
// EPI: 0 = split-K partials (f32), 1 = f32 out + bias (n<Nvalid), 2 = bf16 out into
//      embb h2-half (col n==0 zeroed). BF16B: B is bf16 (plain copy staging) else f32.

template <int EPI, bool BF16B>
__global__ __launch_bounds__(256) void gemm_k(
        const __bf16* __restrict__ A, int lda,
        const void* __restrict__ Bv, int ldb,
        int Nvalid, int kIters, int kChunk,
        float* __restrict__ Cf, int ldc, const float* __restrict__ bias,
        __bf16* __restrict__ Cb) {
    __shared__ __align__(16) __bf16 As[BM][LDT];
    __shared__ __align__(16) __bf16 Bs[BN][LDT];

    const int tid = threadIdx.x;
    const int m0 = blockIdx.x * BM;
    const int n0 = blockIdx.y * BN;
    const int z = blockIdx.z;

    int it0 = z * kChunk;
    int it1 = it0 + kChunk;
    if (it1 > kIters) it1 = kIters;

    const int wave = tid >> 6;
    const int lane = tid & 63;
    const int wm = (wave & 1) * 64;
    const int wn = (wave >> 1) * 64;
    const int fl = lane & 15;
    const int fq = lane >> 4;

    const int srow = tid >> 1;       // 0..127
    const int spart = tid & 1;       // k offset 0/32

    f32x4 acc[4][4] = {};

    const int bn = n0 + srow;
    const bool nok = bn < Nvalid;

    for (int it = it0; it < it1; ++it) {
        int k0 = it * BK;

        // stage A: 32 bf16 per thread
        {
            const uint4* Ag = (const uint4*)(A + (size_t)(m0 + srow) * lda + k0 + spart * 32);
            uint4 av[4];
#pragma unroll
            for (int i = 0; i < 4; ++i) av[i] = Ag[i];
#pragma unroll
            for (int i = 0; i < 4; ++i)
                *(uint4*)&As[srow][spart * 32 + i * 8] = av[i];
        }
        // stage B
        if (BF16B) {
            uint4 bv[4];
            if (nok) {
                const uint4* Bg = (const uint4*)((const __bf16*)Bv + (size_t)bn * ldb + k0 + spart * 32);
#pragma unroll
                for (int i = 0; i < 4; ++i) bv[i] = Bg[i];
            } else {
#pragma unroll
                for (int i = 0; i < 4; ++i) bv[i] = make_uint4(0, 0, 0, 0);
            }
#pragma unroll
            for (int i = 0; i < 4; ++i)
                *(uint4*)&Bs[srow][spart * 32 + i * 8] = bv[i];
        } else {
            __align__(16) __bf16 bl[32];
            if (nok) {
                const float4* Bg = (const float4*)((const float*)Bv + (size_t)bn * ldb + k0 + spart * 32);
                float4 f[8];
#pragma unroll
                for (int j = 0; j < 8; ++j) f[j] = Bg[j];
#pragma unroll
                for (int j = 0; j < 8; ++j) {
                    bl[4 * j] = (__bf16)f[j].x;
                    bl[4 * j + 1] = (__bf16)f[j].y;
                    bl[4 * j + 2] = (__bf16)f[j].z;
                    bl[4 * j + 3] = (__bf16)f[j].w;
                }
            } else {
#pragma unroll
                for (int j = 0; j < 32; ++j) bl[j] = (__bf16)0.f;
            }
#pragma unroll
            for (int q = 0; q < 4; ++q)
                *(uint4*)&Bs[srow][spart * 32 + q * 8] = *(uint4*)&bl[q * 8];
        }
        __syncthreads();

#pragma unroll
        for (int ks = 0; ks < 2; ++ks) {
            int kk = ks * 32 + fq * 8;
            bf16x8 af[4], bf[4];
#pragma unroll
            for (int i = 0; i < 4; ++i)
                af[i] = *(const bf16x8*)&As[wm + i * 16 + fl][kk];
#pragma unroll
            for (int j = 0; j < 4; ++j)
                bf[j] = *(const bf16x8*)&Bs[wn + j * 16 + fl][kk];
#pragma unroll
            for (int i = 0; i < 4; ++i)
#pragma unroll
                for (int j = 0; j < 4; ++j)
                    acc[i][j] = __builtin_amdgcn_mfma_f32_16x16x32_bf16(
                        af[i], bf[j], acc[i][j], 0, 0, 0);
        }
        __syncthreads();
    }

    // epilogue
#pragma unroll
    for (int i = 0; i < 4; ++i) {
#pragma unroll
        for (int j = 0; j < 4; ++j) {
#pragma unroll
            for (int r = 0; r < 4; ++r) {
                int m = m0 + wm + i * 16 + fq * 4 + r;
                int n = n0 + wn + j * 16 + fl;
                float v = acc[i][j][r];
                if (EPI == 0) {
                    Cf[((size_t)z * NN + m) * H2 + n] = v;
                } else if (EPI == 1) {
                    if (n < Nvalid) Cf[(size_t)m * ldc + n] = v + bias[n];
                } else {
                    if (n < Nvalid)
                        Cb[(size_t)m * KP1 + NODELEN + n] = (n == 0) ? (__bf16)0.f : (__bf16)v;
                }
            }
        }
    }
}

// h = relu(sum_z partials + b_e2)
__global__ void k_reduce(const float* __restrict__ partials,
                         const float* __restrict__ bias, float* __restrict__ h) {
    int idx = blockIdx.x * 256 + threadIdx.x;
    if (idx >= NN * H2) return;
    float s = 0.f;
#pragma unroll
    for (int zz = 0; zz < SPLITS; ++zz) s += partials[(size_t)zz * NN * H2 + idx];
    s += bias[idx % H2];
    h[idx] = s > 0.f ? s : 0.f;
}

// encoded[m][e] = h[m] . W_e3[e] + b_e3[e]
__global__ void k_enc(const float* __restrict__ h, const float* __restrict__ W,
                      const float* __restrict__ b, float* __restrict__ out) {
    int m = blockIdx.x, e = threadIdx.x;
    const float4* hr = (const float4*)(h + (size_t)m * H2);
    const float4* wr = (const float4*)(W + (size_t)e * H2);
    float s = 0.f;
#pragma unroll 4
    for (int i = 0; i < H2 / 4; ++i) {
        float4 a = hr[i];
        float4 w = wr[i];
        s += a.x * w.x + a.y * w.y + a.z * w.z + a.w * w.w;
    }
    out[(size_t)m * EMB + e] = s + b[e];
}

// hd_b[m][j] = bf16(relu(enc[m] . W_d1[j] + b_d1[j]))
__global__ void k_dec1(const float* __restrict__ enc, const float* __restrict__ W,
                       const float* __restrict__ b, __bf16* __restrict__ hd) {
    int m = blockIdx.x;
    __shared__ float er[EMB];
    if (threadIdx.x < EMB) er[threadIdx.x] = enc[(size_t)m * EMB + threadIdx.x];
    __syncthreads();
    for (int j = threadIdx.x; j < H2; j += 256) {
        const float4* wr = (const float4*)(W + (size_t)j * EMB);
        float s = 0.f;
#pragma unroll
        for (int i = 0; i < EMB / 4; ++i) {
            float4 w = wr[i];
            s += w.x * er[4 * i] + w.y * er[4 * i + 1] + w.z * er[4 * i + 2] +
                 w.w * er[4 * i + 3];
        }
        float v = s + b[j];
        hd[(size_t)m * H2 + j] = (__bf16)(v > 0.f ? v : 0.f);
    }
}

// ---------------- launch ----------------

extern "C" void kernel_launch(void* const* d_in, const int* in_sizes, int n_in,
                              void* d_out, int out_size, void* d_ws, size_t ws_size,
                              hipStream_t stream) {
    const float* x = (const float*)d_in[0];
    const int* esrc = (const int*)d_in[1];
    const int* edst = (const int*)d_in[2];
    const float* W_e2 = (const float*)d_in[3];
    const float* b_e2 = (const float*)d_in[4];
    const float* W_e3 = (const float*)d_in[5];
    const float* b_e3 = (const float*)d_in[6];
    const float* W_d1 = (const float*)d_in[7];
    const float* b_d1 = (const float*)d_in[8];
    const float* W_d3 = (const float*)d_in[9];
    const float* b_d3 = (const float*)d_in[10];
    float* out = (float*)d_out;

    char* w = (char*)d_ws;
    auto alloc = [&](size_t bytes) {
        char* p = w;
        w += (bytes + 255) & ~(size_t)255;
        return p;
    };
    __bf16* embb = (__bf16*)alloc((size_t)NN * KP1 * 2);           // 36.77 MB
    __bf16* We2b = (__bf16*)alloc((size_t)H2 * KP1 * 2);           // 55.15 MB
    // scratch union: [xTb | A | A2b | cnt | invdeg] overlaid later by partials
    char* uni = (char*)alloc((size_t)SPLITS * NN * H2 * 4);        // 37.75 MB
    __bf16* xTb = (__bf16*)uni;                                    // 17952*512*2 = 18.38 MB
    float* Adj = (float*)(uni + (size_t)17952 * NN * 2);           // 1 MB
    __bf16* A2b = (__bf16*)((char*)Adj + (size_t)NN * NN * 4);     // 0.5 MB
    int* cnt = (int*)((char*)A2b + (size_t)NN * NN * 2);           // 2 KB
    float* invdeg = (float*)((char*)cnt + 2048);                   // 2 KB
    float* partials = (float*)uni;                                 // overlays (safe after h2-GEMM)
    float* h = (float*)alloc((size_t)NN * H2 * 4);
    __bf16* hd_b = (__bf16*)alloc((size_t)NN * H2 * 2);

    // --- adjacency prep ---
    k_zero_int<<<2, 256, 0, stream>>>(cnt, NN);
    k_zero_f4<<<256, 256, 0, stream>>>((float4*)Adj, NN * NN / 4);
    k_deg<<<NE / 256, 256, 0, stream>>>(edst, cnt);
    k_invdeg<<<2, 256, 0, stream>>>(cnt, invdeg);
    k_scatter<<<NE / 256, 256, 0, stream>>>(esrc, edst, invdeg, Adj);
    k_a2<<<NN, 256, 0, stream>>>(Adj, A2b);

    // --- x transpose (bf16) + embb x-half ---
    dim3 gxt((NODELEN + 63) / 64, NN / 64);
    k_xt<<<gxt, 256, 0, stream>>>(x, xTb);
    dim3 gex((NODELEN + 255) / 256, NN);
    k_embx<<<gex, 256, 0, stream>>>(x, embb);

    // --- h2 = A2 @ x  -> embb h2-half (bf16, col0 zero) ---
    dim3 gh2(NN / BM, (NODELEN + BN - 1) / BN, 1);
    gemm_k<2, true><<<gh2, 256, 0, stream>>>(
        A2b, NN, xTb, NN, NODELEN, NN / BK, NN / BK,
        (float*)nullptr, 0, (const float*)nullptr, embb);

    // --- W_e2 -> bf16 padded ---
    k_cvt_we2<<<(H2 * (KP1 / 8) + 255) / 256, 256, 0, stream>>>(W_e2, We2b);

    // --- GEMM1: emb @ W_e2^T, split-K (overlays scratch with partials) ---
    dim3 g1(NN / BM, H2 / BN, SPLITS);
    gemm_k<0, true><<<g1, 256, 0, stream>>>(
        embb, KP1, We2b, KP1, H2, KITERS1, KCHUNK1,
        partials, 0, (const float*)nullptr, (__bf16*)nullptr);

    k_reduce<<<(NN * H2) / 256, 256, 0, stream>>>(partials, b_e2, h);

    // --- encoded ---
    k_enc<<<NN, EMB, 0, stream>>>(h, W_e3, b_e3, out);

    // --- decoder hidden (bf16) ---
    k_dec1<<<NN, 256, 0, stream>>>(out, W_d1, b_d1, hd_b);

    // --- GEMM4: decoded = h_d @ W_d3^T + b_d3 ---
    dim3 g4(NN / BM, (IN_DIM + BN - 1) / BN, 1);
    gemm_k<1, false><<<g4, 256, 0, stream>>>(
        hd_b, H2, W_d3, H2, IN_DIM, H2 / BK, H2 / BK,
        out + (size_t)NN * EMB, IN_DIM, b_d3, (__bf16*)nullptr);
}